// Round 3
// baseline (1479.212 us; speedup 1.0000x reference)
//
#include <hip/hip_runtime.h>
#include <hip/hip_bf16.h>

#define L_NUM 20
#define CC 128
#define TB 8192
#define BB 8
#define TT 64

#define NCONV (L_NUM * 3 * 256 * 128)
#define NMAT  (L_NUM * 128 * 128)
#define XN    ((size_t)BB * TB * CC)   // elements per bf16 x plane

typedef __attribute__((ext_vector_type(4))) float f32x4;
typedef __attribute__((ext_vector_type(8))) short bf16x8;
typedef unsigned int u32;

static const int DILS[L_NUM] = {1, 2, 4, 8, 16, 32, 64, 128, 256, 512,
                                1, 2, 4, 8, 16, 32, 64, 128, 256, 512};

__device__ __forceinline__ unsigned short f2b(float f) {
  union { __hip_bfloat16 h; unsigned short u; } cv;
  cv.h = __float2bfloat16(f);
  return cv.u;
}
__device__ __forceinline__ float b2fu(u32 u) {
  union { u32 u; float f; } cv;
  cv.u = u << 16;
  return cv.f;
}

// byte offset into a [64 t][128 c] bf16 LDS tile, XOR-swizzled (G4)
__device__ __forceinline__ int swz(int t, int cbyte) {
  return (t * 256 + cbyte) ^ ((t & 7) << 4);
}

__global__ void prep_kernel(const float* __restrict__ Wconv,
                            const float* __restrict__ Wout,
                            const float* __restrict__ Wskip,
                            unsigned short* __restrict__ wc,
                            unsigned short* __restrict__ wo,
                            unsigned short* __restrict__ wsk,
                            unsigned short* __restrict__ zp) {
  int i = blockIdx.x * 256 + threadIdx.x;
  if (i < 128) zp[i] = 0;
  if (i < NCONV) {
    // dst [l][k][o][c] <- src [l][o][c][k]
    int c = i & 127;
    int o = (i >> 7) & 255;
    int lk = i >> 15;
    int k = lk % 3;
    int l = lk / 3;
    wc[i] = f2b(Wconv[((size_t)(l * 256 + o) * 128 + c) * 3 + k]);
  }
  if (i < NMAT) {
    wo[i]  = f2b(Wout[i]);
    wsk[i] = f2b(Wskip[i]);
  }
}

// x0 f32 [B][C][T] -> hi/lo bf16 [B][T][C] (plain linear layout)
__global__ __launch_bounds__(256) void x0t_kernel(const float* __restrict__ x0,
                                                  unsigned short* __restrict__ hi,
                                                  unsigned short* __restrict__ lo) {
  __shared__ unsigned short Hs[TT * CC], Ls[TT * CC];
  const int tid = threadIdx.x, lane = tid & 63, w = tid >> 6;
  const int b = blockIdx.y, t0 = blockIdx.x * TT;
  const float* xb = x0 + (size_t)b * CC * TB;
#pragma unroll
  for (int it = 0; it < 8; ++it) {
    int c0 = it * 16 + w * 4;
    u32 hu[4], lu[4];
#pragma unroll
    for (int i2 = 0; i2 < 4; ++i2) {
      float v = xb[(size_t)(c0 + i2) * TB + t0 + lane];
      unsigned short h = f2b(v);
      hu[i2] = h;
      lu[i2] = f2b(v - b2fu(h));
    }
    uint2 hp, lp;
    hp.x = hu[0] | (hu[1] << 16); hp.y = hu[2] | (hu[3] << 16);
    lp.x = lu[0] | (lu[1] << 16); lp.y = lu[2] | (lu[3] << 16);
    *reinterpret_cast<uint2*>(reinterpret_cast<char*>(Hs) + swz(lane, c0 * 2)) = hp;
    *reinterpret_cast<uint2*>(reinterpret_cast<char*>(Ls) + swz(lane, c0 * 2)) = lp;
  }
  __syncthreads();
  unsigned short* hb = hi + ((size_t)b * TB + t0) * CC;
  unsigned short* lb = lo + ((size_t)b * TB + t0) * CC;
#pragma unroll
  for (int it = 0; it < 4; ++it) {
    int o = it * 4096 + tid * 16;
    int t = o >> 8;
    int cl = o & 255;
    int li = t * 256 + (cl ^ ((t & 7) << 4));
    *reinterpret_cast<f32x4*>(reinterpret_cast<char*>(hb) + (size_t)t * 256 + cl) =
        *reinterpret_cast<f32x4*>(reinterpret_cast<char*>(Hs) + li);
    *reinterpret_cast<f32x4*>(reinterpret_cast<char*>(lb) + (size_t)t * 256 + cl) =
        *reinterpret_cast<f32x4*>(reinterpret_cast<char*>(Ls) + li);
  }
}

__global__ __launch_bounds__(256, 3) void layer_kernel(
    const unsigned short* __restrict__ hin,   // [B][T][C] bf16 hi plane
    unsigned short* __restrict__ hout,        // (unused if last)
    unsigned short* __restrict__ lob,         // [B][T][C] bf16 lo plane
    const unsigned short* __restrict__ zpage, // 256B zeros
    const unsigned short* __restrict__ Wc,    // [3][256][128] bf16
    const float* __restrict__ bconv,          // [256]
    const unsigned short* __restrict__ Wo,    // [128][128] bf16
    const float* __restrict__ bout,           // [128]
    const unsigned short* __restrict__ Wsk,   // [128][128] bf16
    const float* __restrict__ bskip,          // [128]
    float* __restrict__ skipo,                // [B][S][T] f32 slice
    float* __restrict__ fxout,                // [B][C][T] f32 (last only)
    int dil, int last) {
  __shared__ unsigned short Zs[TT * CC];      // 16 KB z tile only

  const int tid = threadIdx.x;
  const int lane = tid & 63;
  const int w = tid >> 6;
  const int lo16 = lane & 15;
  const int hi4 = lane >> 4;

  // XCD-aware remap: each XCD owns a contiguous 1024-t window (all batches)
  int p = blockIdx.x + (blockIdx.y << 7);   // 0..1023 dispatch-linear
  int xcd = p & 7, ii = p >> 3;
  int bx = (xcd << 4) | (ii >> 3);          // 0..127
  int b = ii & 7;
  int t0 = bx * TT;

  const unsigned short* hb = hin + (size_t)b * TB * CC;

  // biases for the gated activation (needed right after GEMM1)
  float bcA[2][4], bcG[2][4];
#pragma unroll
  for (int r = 0; r < 2; ++r)
#pragma unroll
    for (int reg = 0; reg < 4; ++reg) {
      int row = w * 32 + r * 16 + hi4 * 4 + reg;
      bcA[r][reg] = bconv[row];
      bcG[r][reg] = bconv[128 + row];
    }

  // ---- conv GEMM: y[256][64] = sum_k Wk(256x128) @ X(t-(2-k)d)[128x64]
  // B-fragments loaded DIRECTLY from the linear [t][c] hi plane.
  f32x4 zero4 = {0.f, 0.f, 0.f, 0.f};
  f32x4 accA[2][4], accG[2][4];
#pragma unroll
  for (int r = 0; r < 2; ++r)
#pragma unroll
    for (int j = 0; j < 4; ++j) { accA[r][j] = zero4; accG[r][j] = zero4; }

#pragma unroll
  for (int k = 0; k < 3; ++k) {
    const unsigned short* Wk = Wc + k * 256 * 128;
    int tb = t0 - (2 - k) * dil;
    const unsigned short* rowp[4];
#pragma unroll
    for (int j = 0; j < 4; ++j) {
      int tg = tb + j * 16 + lo16;
      rowp[j] = (tg >= 0) ? (hb + (size_t)tg * CC) : zpage;
    }
#pragma unroll
    for (int kk = 0; kk < 4; ++kk) {
      int c0 = kk * 32 + hi4 * 8;
      bf16x8 aA0 = *reinterpret_cast<const bf16x8*>(Wk + (w * 32 + lo16) * 128 + c0);
      bf16x8 aA1 = *reinterpret_cast<const bf16x8*>(Wk + (w * 32 + 16 + lo16) * 128 + c0);
      bf16x8 aG0 = *reinterpret_cast<const bf16x8*>(Wk + (128 + w * 32 + lo16) * 128 + c0);
      bf16x8 aG1 = *reinterpret_cast<const bf16x8*>(Wk + (128 + w * 32 + 16 + lo16) * 128 + c0);
#pragma unroll
      for (int j = 0; j < 4; ++j) {
        bf16x8 bx8 = *reinterpret_cast<const bf16x8*>(rowp[j] + c0);
        accA[0][j] = __builtin_amdgcn_mfma_f32_16x16x32_bf16(aA0, bx8, accA[0][j], 0, 0, 0);
        accA[1][j] = __builtin_amdgcn_mfma_f32_16x16x32_bf16(aA1, bx8, accA[1][j], 0, 0, 0);
        accG[0][j] = __builtin_amdgcn_mfma_f32_16x16x32_bf16(aG0, bx8, accG[0][j], 0, 0, 0);
        accG[1][j] = __builtin_amdgcn_mfma_f32_16x16x32_bf16(aG1, bx8, accG[1][j], 0, 0, 0);
      }
    }
  }

  // ---- gated activation -> z bf16 tile into Zs (swizzled)
#pragma unroll
  for (int r = 0; r < 2; ++r) {
#pragma unroll
    for (int j = 0; j < 4; ++j) {
      u32 zu[4];
#pragma unroll
      for (int reg = 0; reg < 4; ++reg) {
        float a = accA[r][j][reg] + bcA[r][reg];
        float g = accG[r][j][reg] + bcG[r][reg];
        float ea = __expf(2.f * a);
        float th = (ea - 1.f) / (ea + 1.f);
        float sg = 1.f / (1.f + __expf(-g));
        zu[reg] = f2b(th * sg);
      }
      uint2 pz;
      pz.x = zu[0] | (zu[1] << 16);
      pz.y = zu[2] | (zu[3] << 16);
      int t = j * 16 + lo16;
      int cB = w * 32 + r * 16 + hi4 * 4;
      *reinterpret_cast<uint2*>(reinterpret_cast<char*>(Zs) + swz(t, cB * 2)) = pz;
    }
  }
  __syncthreads();  // the ONLY barrier

  // prefetch epilogue operands: residual hi/lo + biases (consumed after GEMM2)
  const unsigned short* lb = lob + (size_t)b * TB * CC;
  uint2 hres[2][4], lres[2][4];
  float bsk[2][4], bo[2][4];
#pragma unroll
  for (int r = 0; r < 2; ++r)
#pragma unroll
    for (int j = 0; j < 4; ++j) {
      int t = t0 + j * 16 + lo16;
      int cB = w * 32 + r * 16 + hi4 * 4;
      hres[r][j] = *reinterpret_cast<const uint2*>(hb + (size_t)t * CC + cB);
      lres[r][j] = *reinterpret_cast<const uint2*>(lb + (size_t)t * CC + cB);
    }
#pragma unroll
  for (int r = 0; r < 2; ++r)
#pragma unroll
    for (int reg = 0; reg < 4; ++reg) {
      int row = w * 32 + r * 16 + hi4 * 4 + reg;
      bsk[r][reg] = bskip[row];
      bo[r][reg] = bout[row];
    }

  // ---- skip/out GEMMs: [128x128] @ z[128x64]
  f32x4 accS[2][4], accO[2][4];
#pragma unroll
  for (int r = 0; r < 2; ++r)
#pragma unroll
    for (int j = 0; j < 4; ++j) { accS[r][j] = zero4; accO[r][j] = zero4; }

#pragma unroll
  for (int kk = 0; kk < 4; ++kk) {
    int c0 = kk * 32 + hi4 * 8;
    bf16x8 aS0 = *reinterpret_cast<const bf16x8*>(Wsk + (w * 32 + lo16) * 128 + c0);
    bf16x8 aS1 = *reinterpret_cast<const bf16x8*>(Wsk + (w * 32 + 16 + lo16) * 128 + c0);
    bf16x8 aO0 = *reinterpret_cast<const bf16x8*>(Wo + (w * 32 + lo16) * 128 + c0);
    bf16x8 aO1 = *reinterpret_cast<const bf16x8*>(Wo + (w * 32 + 16 + lo16) * 128 + c0);
#pragma unroll
    for (int j = 0; j < 4; ++j) {
      bf16x8 bz = *reinterpret_cast<const bf16x8*>(
          reinterpret_cast<const char*>(Zs) + swz(j * 16 + lo16, c0 * 2));
      accS[0][j] = __builtin_amdgcn_mfma_f32_16x16x32_bf16(aS0, bz, accS[0][j], 0, 0, 0);
      accS[1][j] = __builtin_amdgcn_mfma_f32_16x16x32_bf16(aS1, bz, accS[1][j], 0, 0, 0);
      accO[0][j] = __builtin_amdgcn_mfma_f32_16x16x32_bf16(aO0, bz, accO[0][j], 0, 0, 0);
      accO[1][j] = __builtin_amdgcn_mfma_f32_16x16x32_bf16(aO1, bz, accO[1][j], 0, 0, 0);
    }
  }

  // ---- epilogue: skip store, residual add, x hi/lo (or f32 fx) store
  float* skb = skipo + (size_t)b * CC * TB;
  float* fxb = fxout + (size_t)b * CC * TB;
  unsigned short* hrow = hout + (size_t)b * TB * CC;
  unsigned short* lrow = lob + (size_t)b * TB * CC;

#pragma unroll
  for (int r = 0; r < 2; ++r) {
#pragma unroll
    for (int j = 0; j < 4; ++j) {
      int t = j * 16 + lo16;
      int cB = w * 32 + r * 16 + hi4 * 4;
      u32 hu[4] = {hres[r][j].x & 0xffffu, hres[r][j].x >> 16,
                   hres[r][j].y & 0xffffu, hres[r][j].y >> 16};
      u32 lu[4] = {lres[r][j].x & 0xffffu, lres[r][j].x >> 16,
                   lres[r][j].y & 0xffffu, lres[r][j].y >> 16};
#pragma unroll
      for (int reg = 0; reg < 4; ++reg)
        skb[(size_t)(cB + reg) * TB + t0 + t] = accS[r][j][reg] + bsk[r][reg];
      if (last) {
        // z readback: this thread's own cells, no barrier needed
        uint2 zp2 = *reinterpret_cast<const uint2*>(
            reinterpret_cast<const char*>(Zs) + swz(t, cB * 2));
        u32 zu[4] = {zp2.x & 0xffffu, zp2.x >> 16, zp2.y & 0xffffu, zp2.y >> 16};
#pragma unroll
        for (int reg = 0; reg < 4; ++reg)
          fxb[(size_t)(cB + reg) * TB + t0 + t] =
              b2fu(zu[reg]) + b2fu(hu[reg]) + b2fu(lu[reg]);
      } else {
        u32 ho[4], lo4[4];
#pragma unroll
        for (int reg = 0; reg < 4; ++reg) {
          float v = accO[r][j][reg] + bo[r][reg] + b2fu(hu[reg]) + b2fu(lu[reg]);
          unsigned short h = f2b(v);
          ho[reg] = h;
          lo4[reg] = f2b(v - b2fu(h));
        }
        uint2 hq, lq;
        hq.x = ho[0] | (ho[1] << 16); hq.y = ho[2] | (ho[3] << 16);
        lq.x = lo4[0] | (lo4[1] << 16); lq.y = lo4[2] | (lo4[3] << 16);
        *reinterpret_cast<uint2*>(hrow + (size_t)(t0 + t) * CC + cB) = hq;
        *reinterpret_cast<uint2*>(lrow + (size_t)(t0 + t) * CC + cB) = lq;
      }
    }
  }
}

extern "C" void kernel_launch(void* const* d_in, const int* in_sizes, int n_in,
                              void* d_out, int out_size, void* d_ws, size_t ws_size,
                              hipStream_t stream) {
  const float* x0    = (const float*)d_in[0];
  const float* Wconv = (const float*)d_in[1];
  const float* bconv = (const float*)d_in[2];
  const float* Wout  = (const float*)d_in[3];
  const float* bout  = (const float*)d_in[4];
  const float* Wskip = (const float*)d_in[5];
  const float* bskip = (const float*)d_in[6];

  unsigned short* wc  = (unsigned short*)d_ws;   // [L][3][256][128] bf16
  unsigned short* wo  = wc + NCONV;              // [L][128][128] bf16
  unsigned short* wsk = wo + NMAT;               // [L][128][128] bf16
  unsigned short* zp  = wsk + NMAT;              // 256B zero page
  unsigned short* hiA = zp + 128;                // [B][T][C] bf16 hi plane A
  unsigned short* lob = hiA + XN;                // [B][T][C] bf16 lo plane

  float* fx = (float*)d_out;                      // final x region [B][C][T]
  float* skips = fx + XN;                         // [L][B][S][T]
  unsigned short* hiB = (unsigned short*)d_out;   // hi plane B aliased in x region
  // parity: x0t->hiB; even layers read hiB write hiA; odd read hiA write hiB.
  // l19 (odd) reads hiA and writes f32 over hiB's region -> no race.

  prep_kernel<<<(NCONV + 255) / 256, 256, 0, stream>>>(Wconv, Wout, Wskip, wc, wo, wsk, zp);
  x0t_kernel<<<dim3(TB / TT, BB), 256, 0, stream>>>(x0, hiB, lob);

  for (int l = 0; l < L_NUM; ++l) {
    const unsigned short* hin = (l % 2 == 0) ? hiB : hiA;
    unsigned short* hout      = (l % 2 == 0) ? hiA : hiB;
    layer_kernel<<<dim3(TB / TT, BB), 256, 0, stream>>>(
        hin, hout, lob, zp,
        wc + (size_t)l * 3 * 256 * 128, bconv + (size_t)l * 256,
        wo + (size_t)l * 128 * 128, bout + (size_t)l * 128,
        wsk + (size_t)l * 128 * 128, bskip + (size_t)l * 128,
        skips + (size_t)l * XN, fx,
        DILS[l], l == L_NUM - 1 ? 1 : 0);
  }
}

// Round 4
// 1075.437 us; speedup vs baseline: 1.3755x; 1.3755x over previous
//
#include <hip/hip_runtime.h>
#include <hip/hip_bf16.h>

#define L_NUM 20
#define CC 128
#define TB 8192
#define BB 8
#define TT 64

#define NCONV (L_NUM * 3 * 256 * 128)
#define NMAT  (L_NUM * 128 * 128)
#define XN    ((size_t)BB * TB * CC)   // elements per bf16 x plane

typedef __attribute__((ext_vector_type(4))) float f32x4;
typedef __attribute__((ext_vector_type(8))) short bf16x8;
typedef unsigned int u32;

static const int DILS[L_NUM] = {1, 2, 4, 8, 16, 32, 64, 128, 256, 512,
                                1, 2, 4, 8, 16, 32, 64, 128, 256, 512};

__device__ __forceinline__ unsigned short f2b(float f) {
  union { __hip_bfloat16 h; unsigned short u; } cv;
  cv.h = __float2bfloat16(f);
  return cv.u;
}
__device__ __forceinline__ float b2fu(u32 u) {
  union { u32 u; float f; } cv;
  cv.u = u << 16;
  return cv.f;
}

// byte offset into a [64 t][128 c] bf16 LDS tile, XOR-swizzled (G4)
__device__ __forceinline__ int swz(int t, int cbyte) {
  return (t * 256 + cbyte) ^ ((t & 7) << 4);
}

// async global->LDS, 16B per lane; LDS dest = wave-uniform base + lane*16
__device__ __forceinline__ void gload16(const void* g, void* l) {
  __builtin_amdgcn_global_load_lds(
      (const __attribute__((address_space(1))) u32*)g,
      (__attribute__((address_space(3))) u32*)l, 16, 0, 0);
}

__global__ void prep_kernel(const float* __restrict__ Wconv,
                            const float* __restrict__ Wout,
                            const float* __restrict__ Wskip,
                            unsigned short* __restrict__ wc,
                            unsigned short* __restrict__ wo,
                            unsigned short* __restrict__ wsk,
                            unsigned short* __restrict__ zp) {
  int i = blockIdx.x * 256 + threadIdx.x;
  if (i < 128) zp[i] = 0;
  if (i < NCONV) {
    // dst [l][k][o][c] <- src [l][o][c][k]
    int c = i & 127;
    int o = (i >> 7) & 255;
    int lk = i >> 15;
    int k = lk % 3;
    int l = lk / 3;
    wc[i] = f2b(Wconv[((size_t)(l * 256 + o) * 128 + c) * 3 + k]);
  }
  if (i < NMAT) {
    wo[i]  = f2b(Wout[i]);
    wsk[i] = f2b(Wskip[i]);
  }
}

// x0 f32 [B][C][T] -> hi/lo bf16 [B][T][C] (plain linear layout)
__global__ __launch_bounds__(256) void x0t_kernel(const float* __restrict__ x0,
                                                  unsigned short* __restrict__ hi,
                                                  unsigned short* __restrict__ lo) {
  __shared__ unsigned short Hs[TT * CC], Ls[TT * CC];
  const int tid = threadIdx.x, lane = tid & 63, w = tid >> 6;
  const int b = blockIdx.y, t0 = blockIdx.x * TT;
  const float* xb = x0 + (size_t)b * CC * TB;
#pragma unroll
  for (int it = 0; it < 8; ++it) {
    int c0 = it * 16 + w * 4;
    u32 hu[4], lu[4];
#pragma unroll
    for (int i2 = 0; i2 < 4; ++i2) {
      float v = xb[(size_t)(c0 + i2) * TB + t0 + lane];
      unsigned short h = f2b(v);
      hu[i2] = h;
      lu[i2] = f2b(v - b2fu(h));
    }
    uint2 hp, lp;
    hp.x = hu[0] | (hu[1] << 16); hp.y = hu[2] | (hu[3] << 16);
    lp.x = lu[0] | (lu[1] << 16); lp.y = lu[2] | (lu[3] << 16);
    *reinterpret_cast<uint2*>(reinterpret_cast<char*>(Hs) + swz(lane, c0 * 2)) = hp;
    *reinterpret_cast<uint2*>(reinterpret_cast<char*>(Ls) + swz(lane, c0 * 2)) = lp;
  }
  __syncthreads();
  unsigned short* hb = hi + ((size_t)b * TB + t0) * CC;
  unsigned short* lb = lo + ((size_t)b * TB + t0) * CC;
#pragma unroll
  for (int it = 0; it < 4; ++it) {
    int o = it * 4096 + tid * 16;
    int t = o >> 8;
    int cl = o & 255;
    int li = t * 256 + (cl ^ ((t & 7) << 4));
    // Hs[li] holds value (t, cl) -> store plain [t][c]
    *reinterpret_cast<f32x4*>(reinterpret_cast<char*>(hb) + (size_t)t * 256 + cl) =
        *reinterpret_cast<f32x4*>(reinterpret_cast<char*>(Hs) + li);
    *reinterpret_cast<f32x4*>(reinterpret_cast<char*>(lb) + (size_t)t * 256 + cl) =
        *reinterpret_cast<f32x4*>(reinterpret_cast<char*>(Ls) + li);
  }
}

__global__ __launch_bounds__(512, 4) void layer_kernel(
    const unsigned short* __restrict__ hin,   // [B][T][C] bf16 hi plane
    unsigned short* __restrict__ hout,        // (unused if last)
    unsigned short* __restrict__ lob,         // [B][T][C] bf16 lo plane
    const unsigned short* __restrict__ zpage, // 256B zeros
    const unsigned short* __restrict__ Wc,    // [3][256][128] bf16
    const float* __restrict__ bconv,          // [256]
    const unsigned short* __restrict__ Wo,    // [128][128] bf16
    const float* __restrict__ bout,           // [128]
    const unsigned short* __restrict__ Wsk,   // [128][128] bf16
    const float* __restrict__ bskip,          // [128]
    float* __restrict__ skipo,                // [B][S][T] f32 slice
    float* __restrict__ fxout,                // [B][C][T] f32 (last only)
    int dil, int last) {
  __shared__ unsigned short Xs[3][TT * CC];  // 3 tap tiles, 16 KB each
  unsigned short* Zs = &Xs[0][0];            // z overlays tap0 (barriered)

  const int tid = threadIdx.x;
  const int lane = tid & 63;
  const int w = tid >> 6;          // wave 0..7
  const int lo16 = lane & 15;
  const int hi4 = lane >> 4;

  // XCD-aware remap: each XCD owns a contiguous 1024-t window (all batches)
  int p = blockIdx.x + (blockIdx.y << 7);   // 0..1023 dispatch-linear
  int xcd = p & 7, ii = p >> 3;
  int bx = (xcd << 4) | (ii >> 3);          // 0..127
  int b = ii & 7;
  int t0 = bx * TT;

  const unsigned short* hb = hin + (size_t)b * TB * CC;

  // ---- stage 3 taps via global_load_lds (linear LDS, pre-swizzled source)
#pragma unroll
  for (int k = 0; k < 3; ++k) {
    int tbase = t0 + (k - 2) * dil;
#pragma unroll
    for (int i = 0; i < 2; ++i) {
      int o = w * 2048 + i * 1024 + lane * 16;   // byte offset in 16KB tile
      int tl = o >> 8;
      int cb = (o & 255) ^ ((tl & 7) << 4);
      int tg = tbase + tl;
      const char* src = (tg >= 0)
          ? (reinterpret_cast<const char*>(hb + (size_t)tg * CC) + cb)
          : (reinterpret_cast<const char*>(zpage) + cb);
      gload16(src, reinterpret_cast<char*>(&Xs[k][0]) + w * 2048 + i * 1024);
    }
  }
  __syncthreads();  // bar1: taps resident

  // ---- conv GEMM: rows w*16.. of A-half and G-half (16 rows each)
  f32x4 zero4 = {0.f, 0.f, 0.f, 0.f};
  f32x4 accA[4], accG[4];
#pragma unroll
  for (int j = 0; j < 4; ++j) { accA[j] = zero4; accG[j] = zero4; }

#pragma unroll
  for (int k = 0; k < 3; ++k) {
    const unsigned short* Wk = Wc + k * 256 * 128;
#pragma unroll
    for (int kk = 0; kk < 4; ++kk) {
      int c0 = kk * 32 + hi4 * 8;
      bf16x8 aA = *reinterpret_cast<const bf16x8*>(Wk + (w * 16 + lo16) * 128 + c0);
      bf16x8 aG = *reinterpret_cast<const bf16x8*>(Wk + (128 + w * 16 + lo16) * 128 + c0);
#pragma unroll
      for (int j = 0; j < 4; ++j) {
        bf16x8 bx8 = *reinterpret_cast<const bf16x8*>(
            reinterpret_cast<const char*>(&Xs[k][0]) + swz(j * 16 + lo16, c0 * 2));
        accA[j] = __builtin_amdgcn_mfma_f32_16x16x32_bf16(aA, bx8, accA[j], 0, 0, 0);
        accG[j] = __builtin_amdgcn_mfma_f32_16x16x32_bf16(aG, bx8, accG[j], 0, 0, 0);
      }
    }
  }

  // ---- gated activation into registers (rcp/exp2 form)
  f32x4 bca = *reinterpret_cast<const f32x4*>(bconv + w * 16 + hi4 * 4);
  f32x4 bcg = *reinterpret_cast<const f32x4*>(bconv + 128 + w * 16 + hi4 * 4);
  uint2 zpk[4];
#pragma unroll
  for (int j = 0; j < 4; ++j) {
    u32 zu[4];
#pragma unroll
    for (int reg = 0; reg < 4; ++reg) {
      float a = accA[j][reg] + bca[reg];
      float g = accG[j][reg] + bcg[reg];
      float ea = __builtin_amdgcn_exp2f(2.885390081777927f * a);      // e^{2a}
      float th = 1.f - 2.f * __builtin_amdgcn_rcpf(1.f + ea);          // tanh(a)
      float sg = __builtin_amdgcn_rcpf(
          1.f + __builtin_amdgcn_exp2f(-1.4426950408889634f * g));     // sigmoid(g)
      zu[reg] = f2b(th * sg);
    }
    zpk[j].x = zu[0] | (zu[1] << 16);
    zpk[j].y = zu[2] | (zu[3] << 16);
  }

  // prefetch epilogue operands (consumed after GEMM2; hidden under it)
  const unsigned short* lb = lob + (size_t)b * TB * CC;
  uint2 hres[4], lres[4];
#pragma unroll
  for (int j = 0; j < 4; ++j) {
    int t = t0 + j * 16 + lo16;
    int cB = w * 16 + hi4 * 4;
    hres[j] = *reinterpret_cast<const uint2*>(hb + (size_t)t * CC + cB);
    lres[j] = *reinterpret_cast<const uint2*>(lb + (size_t)t * CC + cB);
  }
  f32x4 bsk = *reinterpret_cast<const f32x4*>(bskip + w * 16 + hi4 * 4);
  f32x4 bo  = *reinterpret_cast<const f32x4*>(bout + w * 16 + hi4 * 4);

  __syncthreads();  // bar2: all GEMM1 tap reads complete

  // z write: channels cB..cB+3 at t = j*16+lo16 (overlays tap0)
#pragma unroll
  for (int j = 0; j < 4; ++j) {
    int cB = w * 16 + hi4 * 4;
    *reinterpret_cast<uint2*>(reinterpret_cast<char*>(Zs) +
                              swz(j * 16 + lo16, cB * 2)) = zpk[j];
  }
  __syncthreads();  // bar3: z tile complete

  // ---- skip/out GEMMs: rows w*16.. of S and O (16 rows each)
  f32x4 accS[4], accO[4];
#pragma unroll
  for (int j = 0; j < 4; ++j) { accS[j] = zero4; accO[j] = zero4; }

#pragma unroll
  for (int kk = 0; kk < 4; ++kk) {
    int c0 = kk * 32 + hi4 * 8;
    bf16x8 aS = *reinterpret_cast<const bf16x8*>(Wsk + (w * 16 + lo16) * 128 + c0);
    bf16x8 aO = *reinterpret_cast<const bf16x8*>(Wo + (w * 16 + lo16) * 128 + c0);
#pragma unroll
    for (int j = 0; j < 4; ++j) {
      bf16x8 bz = *reinterpret_cast<const bf16x8*>(
          reinterpret_cast<const char*>(Zs) + swz(j * 16 + lo16, c0 * 2));
      accS[j] = __builtin_amdgcn_mfma_f32_16x16x32_bf16(aS, bz, accS[j], 0, 0, 0);
      accO[j] = __builtin_amdgcn_mfma_f32_16x16x32_bf16(aO, bz, accO[j], 0, 0, 0);
    }
  }

  // ---- epilogue: skip store, residual add, hi/lo (or f32 fx) store
  float* skb = skipo + (size_t)b * CC * TB;
  float* fxb = fxout + (size_t)b * CC * TB;
  unsigned short* hrow = hout + (size_t)b * TB * CC;
  unsigned short* lrow = lob + (size_t)b * TB * CC;

#pragma unroll
  for (int j = 0; j < 4; ++j) {
    int t = j * 16 + lo16;
    int cB = w * 16 + hi4 * 4;
    u32 hu[4] = {hres[j].x & 0xffffu, hres[j].x >> 16,
                 hres[j].y & 0xffffu, hres[j].y >> 16};
    u32 lu[4] = {lres[j].x & 0xffffu, lres[j].x >> 16,
                 lres[j].y & 0xffffu, lres[j].y >> 16};
#pragma unroll
    for (int reg = 0; reg < 4; ++reg)
      skb[(size_t)(cB + reg) * TB + t0 + t] = accS[j][reg] + bsk[reg];
    if (last) {
      // z readback: this thread's own cells (stable since bar3)
      uint2 zp2 = *reinterpret_cast<const uint2*>(
          reinterpret_cast<const char*>(Zs) + swz(t, cB * 2));
      u32 zu[4] = {zp2.x & 0xffffu, zp2.x >> 16, zp2.y & 0xffffu, zp2.y >> 16};
#pragma unroll
      for (int reg = 0; reg < 4; ++reg)
        fxb[(size_t)(cB + reg) * TB + t0 + t] =
            b2fu(zu[reg]) + b2fu(hu[reg]) + b2fu(lu[reg]);
    } else {
      u32 ho[4], lo4[4];
#pragma unroll
      for (int reg = 0; reg < 4; ++reg) {
        float v = accO[j][reg] + bo[reg] + b2fu(hu[reg]) + b2fu(lu[reg]);
        unsigned short h = f2b(v);
        ho[reg] = h;
        lo4[reg] = f2b(v - b2fu(h));
      }
      uint2 hq, lq;
      hq.x = ho[0] | (ho[1] << 16); hq.y = ho[2] | (ho[3] << 16);
      lq.x = lo4[0] | (lo4[1] << 16); lq.y = lo4[2] | (lo4[3] << 16);
      *reinterpret_cast<uint2*>(hrow + (size_t)(t0 + t) * CC + cB) = hq;
      *reinterpret_cast<uint2*>(lrow + (size_t)(t0 + t) * CC + cB) = lq;
    }
  }
}

extern "C" void kernel_launch(void* const* d_in, const int* in_sizes, int n_in,
                              void* d_out, int out_size, void* d_ws, size_t ws_size,
                              hipStream_t stream) {
  const float* x0    = (const float*)d_in[0];
  const float* Wconv = (const float*)d_in[1];
  const float* bconv = (const float*)d_in[2];
  const float* Wout  = (const float*)d_in[3];
  const float* bout  = (const float*)d_in[4];
  const float* Wskip = (const float*)d_in[5];
  const float* bskip = (const float*)d_in[6];

  unsigned short* wc  = (unsigned short*)d_ws;   // [L][3][256][128] bf16
  unsigned short* wo  = wc + NCONV;              // [L][128][128] bf16
  unsigned short* wsk = wo + NMAT;               // [L][128][128] bf16
  unsigned short* zp  = wsk + NMAT;              // 256B zero page
  unsigned short* hiA = zp + 128;                // [B][T][C] bf16 hi plane A
  unsigned short* lob = hiA + XN;                // [B][T][C] bf16 lo plane

  float* fx = (float*)d_out;                      // final x region [B][C][T]
  float* skips = fx + XN;                         // [L][B][S][T]
  unsigned short* hiB = (unsigned short*)d_out;   // hi plane B aliased in x region
  // parity: x0t->hiB; even layers read hiB write hiA; odd read hiA write hiB.
  // l19 (odd) reads hiA and writes f32 over hiB's region -> no race.

  prep_kernel<<<(NCONV + 255) / 256, 256, 0, stream>>>(Wconv, Wout, Wskip, wc, wo, wsk, zp);
  x0t_kernel<<<dim3(TB / TT, BB), 256, 0, stream>>>(x0, hiB, lob);

  for (int l = 0; l < L_NUM; ++l) {
    const unsigned short* hin = (l % 2 == 0) ? hiB : hiA;
    unsigned short* hout      = (l % 2 == 0) ? hiA : hiB;
    layer_kernel<<<dim3(TB / TT, BB), 512, 0, stream>>>(
        hin, hout, lob, zp,
        wc + (size_t)l * 3 * 256 * 128, bconv + (size_t)l * 256,
        wo + (size_t)l * 128 * 128, bout + (size_t)l * 128,
        wsk + (size_t)l * 128 * 128, bskip + (size_t)l * 128,
        skips + (size_t)l * XN, fx,
        DILS[l], l == L_NUM - 1 ? 1 : 0);
  }
}